// Round 6
// baseline (2627.894 us; speedup 1.0000x reference)
//
#include <hip/hip_runtime.h>

// GraphSAGE: x(524288,256) -> FC relu -> 3x sage_conv -> out(8192,64)
// R6: B-in-LDS MFMA GEMM (swizzled, K-split for dual), bf16 activations,
//     CSR pull-aggregation.
constexpr int N0c = 524288, N1c = 262144, N2c = 65536, N3c = 8192;

typedef __attribute__((ext_vector_type(8))) short   bf16x8;
typedef __attribute__((ext_vector_type(8))) unsigned short u16x8;
typedef __attribute__((ext_vector_type(4))) float   f32x4;
typedef __attribute__((ext_vector_type(4))) unsigned short u16x4;

__device__ inline unsigned short f2bf(float f) {
    union { float f; unsigned u; } v; v.f = f;
    unsigned r = v.u + 0x7FFF + ((v.u >> 16) & 1);   // RNE
    return (unsigned short)(r >> 16);
}
__device__ inline float bf2f(unsigned short u) {
    union { unsigned u; float f; } v; v.u = ((unsigned)u) << 16;
    return v.f;
}

// transpose + cast one weight: Wt[n][k] = bf16(W[k][n]); K is always 256 here
__global__ __launch_bounds__(256)
void wconv_k(const float* __restrict__ W, unsigned short* __restrict__ Wt, int K, int N)
{
    const int i = blockIdx.x * 256 + threadIdx.x;   // over K*N
    if (i >= K * N) return;
    const int k = i / N, n = i % N;
    Wt[n * K + k] = f2bf(W[i]);
}

__device__ inline bf16x8 pack_bf8(const float* p) {
    const f32x4 u = *(const f32x4*)p;
    const f32x4 v = *(const f32x4*)(p + 4);
    bf16x8 t;
    #pragma unroll
    for (int j = 0; j < 4; ++j) {
        t[j]     = (short)f2bf(u[j]);
        t[j + 4] = (short)f2bf(v[j]);
    }
    return t;
}

// C[M x N] = act( A1 @ Wt1^T (+ A2 @ Wt2^T) + b ), K=256, N=NT*16.
// B staged in LDS (XOR-swizzled). 512 thr = 8 waves; wave owns SPW 16-row strips.
// Single: Bs[N][256] one stage. DUAL: 2 phases, each Bs1/Bs2 [N][128] k-half,
// acc persists in registers across phases.
template<int NT, int SPW, bool RELU, bool DUAL, bool A_F32, bool OUT_BF16>
__global__ __launch_bounds__(512, 2)
void gemm_lds(const void* __restrict__ A1v, const void* __restrict__ A2v,
              const unsigned short* __restrict__ Wt1,
              const unsigned short* __restrict__ Wt2,
              const float* __restrict__ bias, void* __restrict__ Cv)
{
    constexpr int N = NT * 16;
    __shared__ unsigned short Bs[N * 256];   // single: [N][256]; dual: 2x [N][128]

    const int t    = threadIdx.x;
    const int lane = t & 63;
    const int wv   = t >> 6;                 // 0..7
    const int col  = lane & 15;              // B col / A row-in-strip
    const int kg   = lane >> 4;              // k-group
    const int swz  = (col & 7) << 3;         // bank swizzle (ushort units)
    const long brow = (long)blockIdx.x * (8 * SPW * 16);

    const unsigned short* A1h = (const unsigned short*)A1v;
    const float*          A1f = (const float*)A1v;
    const unsigned short* A2h = (const unsigned short*)A2v;

    auto store_strip = [&](int p, const f32x4* accp) {
        const long srow = brow + (wv * SPW + p) * 16;
        #pragma unroll
        for (int nt = 0; nt < NT; ++nt) {
            const int c = nt * 16 + col;
            const float bb = bias[c];
            #pragma unroll
            for (int rr = 0; rr < 4; ++rr) {
                const long row = srow + kg * 4 + rr;
                float o = accp[nt][rr] + bb;
                if constexpr (RELU) o = fmaxf(o, 0.f);
                if constexpr (OUT_BF16)
                    ((unsigned short*)Cv)[row * N + c] = f2bf(o);
                else
                    ((float*)Cv)[row * N + c] = o;
            }
        }
    };

    if constexpr (!DUAL) {
        // ---- stage full B: idx16(n,k) = n*256 + (k ^ ((n&7)<<3)) ----
        #pragma unroll
        for (int i = 0; i < (N * 32) / 512; ++i) {
            const int c = i * 512 + t;              // 16B chunk id
            const u16x8 v = *(const u16x8*)&Wt1[c * 8];
            *(u16x8*)&Bs[(c * 8) ^ (((c >> 5) & 7) << 3)] = v;
        }
        __syncthreads();

        for (int p = 0; p < SPW; ++p) {
            const long r = brow + (wv * SPW + p) * 16 + col;
            f32x4 acc[NT];
            #pragma unroll
            for (int nt = 0; nt < NT; ++nt) acc[nt] = (f32x4){0.f,0.f,0.f,0.f};

            #pragma unroll
            for (int k0 = 0; k0 < 256; k0 += 32) {
                const int kx = (k0 + kg * 8) ^ swz;
                bf16x8 a1;
                if constexpr (A_F32) a1 = pack_bf8(&A1f[r * 256 + k0 + kg * 8]);
                else                 a1 = *(const bf16x8*)&A1h[r * 256 + k0 + kg * 8];
                #pragma unroll
                for (int nt = 0; nt < NT; ++nt) {
                    const bf16x8 b1 = *(const bf16x8*)&Bs[nt * 4096 + col * 256 + kx];
                    acc[nt] = __builtin_amdgcn_mfma_f32_16x16x32_bf16(a1, b1, acc[nt], 0, 0, 0);
                }
            }
            store_strip(p, acc);
        }
    } else {
        // ---- dual with K-split: 2 phases, Bs1/Bs2 hold k-half [N][128] ----
        f32x4 acc[SPW][NT];
        #pragma unroll
        for (int p = 0; p < SPW; ++p)
            #pragma unroll
            for (int nt = 0; nt < NT; ++nt) acc[p][nt] = (f32x4){0.f,0.f,0.f,0.f};

        #pragma unroll
        for (int kh = 0; kh < 2; ++kh) {
            if (kh) __syncthreads();   // phase-0 reads done before restage
            #pragma unroll
            for (int i = 0; i < (N * 32) / 512; ++i) {
                const int c2 = i * 512 + t;
                const int mt = c2 / (N * 16);       // 0: Wt1, 1: Wt2
                const int c  = c2 % (N * 16);
                const int n  = c >> 4;
                const int off = (c & 15) * 8;       // ushort offset in half-row
                const unsigned short* Wsrc = mt ? Wt2 : Wt1;
                const u16x8 v = *(const u16x8*)&Wsrc[n * 256 + kh * 128 + off];
                *(u16x8*)&Bs[mt * (N * 128) + n * 128 + (off ^ ((n & 7) << 3))] = v;
            }
            __syncthreads();

            for (int p = 0; p < SPW; ++p) {
                const long r = brow + (wv * SPW + p) * 16 + col;
                const long ab = r * 256 + kh * 128;
                #pragma unroll
                for (int k0 = 0; k0 < 128; k0 += 32) {
                    const int kx = (k0 + kg * 8) ^ swz;
                    const bf16x8 a1 = *(const bf16x8*)&A1h[ab + k0 + kg * 8];
                    const bf16x8 a2 = *(const bf16x8*)&A2h[ab + k0 + kg * 8];
                    #pragma unroll
                    for (int nt = 0; nt < NT; ++nt) {
                        const bf16x8 b1 = *(const bf16x8*)&Bs[nt * 2048 + col * 128 + kx];
                        acc[p][nt] = __builtin_amdgcn_mfma_f32_16x16x32_bf16(a1, b1, acc[p][nt], 0, 0, 0);
                        const bf16x8 b2 = *(const bf16x8*)&Bs[N * 128 + nt * 2048 + col * 128 + kx];
                        acc[p][nt] = __builtin_amdgcn_mfma_f32_16x16x32_bf16(a2, b2, acc[p][nt], 0, 0, 0);
                    }
                }
            }
        }
        #pragma unroll
        for (int p = 0; p < SPW; ++p) store_strip(p, acc[p]);
    }
}

// ---- CSR build: counting sort of edges by dst ----

__global__ __launch_bounds__(256)
void hist_k(const int* __restrict__ dst, int* __restrict__ hist, int E)
{
    const int i = blockIdx.x * 256 + threadIdx.x;
    if (i < E) atomicAdd(&hist[dst[i]], 1);
}

__global__ __launch_bounds__(256)
void scan1_k(const int* __restrict__ hist, int* __restrict__ offs,
             int* __restrict__ bsum, int n)
{
    __shared__ int sm[256];
    const int t = threadIdx.x;
    const int base = blockIdx.x * 1024 + t * 4;
    int4 v = make_int4(0, 0, 0, 0);
    if (base < n) v = *(const int4*)&hist[base];
    const int s = v.x + v.y + v.z + v.w;
    int val = s;
    sm[t] = val; __syncthreads();
    #pragma unroll
    for (int off = 1; off < 256; off <<= 1) {
        const int add = (t >= off) ? sm[t - off] : 0;
        __syncthreads();
        val += add;
        sm[t] = val;
        __syncthreads();
    }
    const int excl = val - s;
    if (base < n) {
        offs[base]     = excl;
        offs[base + 1] = excl + v.x;
        offs[base + 2] = excl + v.x + v.y;
        offs[base + 3] = excl + v.x + v.y + v.z;
    }
    if (t == 255) bsum[blockIdx.x] = val;
}

__global__ __launch_bounds__(256)
void scan2_k(int* __restrict__ bsum, int nb)
{
    __shared__ int sm[256];
    const int t = threadIdx.x;
    const int s = (t < nb) ? bsum[t] : 0;
    int val = s;
    sm[t] = val; __syncthreads();
    #pragma unroll
    for (int off = 1; off < 256; off <<= 1) {
        const int add = (t >= off) ? sm[t - off] : 0;
        __syncthreads();
        val += add;
        sm[t] = val;
        __syncthreads();
    }
    if (t < nb) bsum[t] = val - s;
}

__global__ __launch_bounds__(256)
void scan3_k(int* __restrict__ offs, const int* __restrict__ bsum)
{
    const int i = blockIdx.x * 256 + threadIdx.x;
    offs[i] += bsum[i >> 10];
}

__global__ __launch_bounds__(256)
void fill_k(const int* __restrict__ src, const int* __restrict__ dst,
            const int* __restrict__ offs, int* __restrict__ hist,
            int* __restrict__ ssrc, int E)
{
    const int i = blockIdx.x * 256 + threadIdx.x;
    if (i < E) {
        const int d = dst[i];
        const int p = atomicAdd(&hist[d], -1) - 1;
        ssrc[offs[d] + p] = src[i];
    }
}

// one wave per dst row: gather+mean bf16 h[src] rows (512 B each), no atomics
__global__ __launch_bounds__(256)
void agg_k(const unsigned short* __restrict__ h, const int* __restrict__ ssrc,
           const int* __restrict__ offs, unsigned short* __restrict__ agg,
           int n, int E)
{
    const int w    = blockIdx.x * 4 + (threadIdx.x >> 6);
    const int lane = threadIdx.x & 63;
    if (w >= n) return;
    const int beg = offs[w];
    const int end = (w == n - 1) ? E : offs[w + 1];
    float acc[4] = {0.f, 0.f, 0.f, 0.f};
    int j = beg;
    for (; j + 7 < end; j += 8) {                  // 8 gathers in flight
        int s[8];
        #pragma unroll
        for (int q = 0; q < 8; ++q) s[q] = ssrc[j + q];
        u16x4 v[8];
        #pragma unroll
        for (int q = 0; q < 8; ++q)
            v[q] = *(const u16x4*)&h[(size_t)s[q] * 256 + lane * 4];
        #pragma unroll
        for (int q = 0; q < 8; ++q)
            #pragma unroll
            for (int c = 0; c < 4; ++c) acc[c] += bf2f(v[q][c]);
    }
    for (; j < end; ++j) {
        const u16x4 v0 = *(const u16x4*)&h[(size_t)ssrc[j] * 256 + lane * 4];
        #pragma unroll
        for (int c = 0; c < 4; ++c) acc[c] += bf2f(v0[c]);
    }
    const float inv = 1.0f / fmaxf((float)(end - beg), 1.0f);
    u16x4 o;
    #pragma unroll
    for (int c = 0; c < 4; ++c) o[c] = f2bf(acc[c] * inv);
    *(u16x4*)&agg[(size_t)w * 256 + lane * 4] = o;
}

static void build_and_aggregate(const unsigned short* h, const int* src, const int* dst,
                                int n, int E, int* hist, int* offs, int* bsum,
                                int* ssrc, unsigned short* agg, hipStream_t stream)
{
    const dim3 blk(256);
    hipMemsetAsync(hist, 0, (size_t)n * 4, stream);
    hist_k<<<dim3((E + 255) / 256), blk, 0, stream>>>(dst, hist, E);
    scan1_k<<<dim3(n / 1024), blk, 0, stream>>>(hist, offs, bsum, n);
    scan2_k<<<dim3(1), blk, 0, stream>>>(bsum, n / 1024);
    scan3_k<<<dim3(n / 256), blk, 0, stream>>>(offs, bsum);
    fill_k<<<dim3((E + 255) / 256), blk, 0, stream>>>(src, dst, offs, hist, ssrc, E);
    agg_k<<<dim3(n / 4), blk, 0, stream>>>(h, ssrc, offs, agg, n, E);
}

extern "C" void kernel_launch(void* const* d_in, const int* in_sizes, int n_in,
                              void* d_out, int out_size, void* d_ws, size_t ws_size,
                              hipStream_t stream)
{
    const float* x    = (const float*)d_in[0];
    const int*   src0 = (const int*)d_in[1];
    const int*   dst0 = (const int*)d_in[2];
    const int*   src1 = (const int*)d_in[3];
    const int*   dst1 = (const int*)d_in[4];
    const int*   src2 = (const int*)d_in[5];
    const int*   dst2 = (const int*)d_in[6];
    const float* Wfc  = (const float*)d_in[10];
    const float* bfc  = (const float*)d_in[11];
    const float* Ws0  = (const float*)d_in[12];
    const float* Wn0  = (const float*)d_in[13];
    const float* b0   = (const float*)d_in[14];
    const float* Ws1  = (const float*)d_in[15];
    const float* Wn1  = (const float*)d_in[16];
    const float* b1   = (const float*)d_in[17];
    const float* Ws2  = (const float*)d_in[18];
    const float* Wn2  = (const float*)d_in[19];
    const float* b2   = (const float*)d_in[20];
    const int E0 = in_sizes[1], E1 = in_sizes[3], E2 = in_sizes[5];

    char* ws = (char*)d_ws;
    unsigned short* h0   = (unsigned short*)ws;                    // 256 MiB
    unsigned short* h1   = (unsigned short*)(ws + (256ULL << 20)); // 128 MiB
    unsigned short* h2   = (unsigned short*)(ws + (384ULL << 20)); //  32 MiB
    unsigned short* agg  = (unsigned short*)(ws + (416ULL << 20)); // 128 MiB
    unsigned short* Wt   = (unsigned short*)(ws + (544ULL << 20)); //   1 MiB
    int*            hist = (int*)(ws + (545ULL << 20));            //   1 MiB
    int*            offs = (int*)(ws + (546ULL << 20));            //   1 MiB
    int*            bsum = (int*)(ws + (547ULL << 20));            //   4 KiB
    int*            ssrc = (int*)(ws + (548ULL << 20));            // <=10.5 MiB

    unsigned short* wfc = Wt;
    unsigned short* ws0 = Wt + 65536;
    unsigned short* wn0 = Wt + 131072;
    unsigned short* ws1 = Wt + 196608;
    unsigned short* wn1 = Wt + 262144;
    unsigned short* ws2 = Wt + 327680;
    unsigned short* wn2 = Wt + 344064;

    const dim3 blk(256);

    // weights -> bf16 transposed [N][K]
    wconv_k<<<dim3(256), blk, 0, stream>>>(Wfc, wfc, 256, 256);
    wconv_k<<<dim3(256), blk, 0, stream>>>(Ws0, ws0, 256, 256);
    wconv_k<<<dim3(256), blk, 0, stream>>>(Wn0, wn0, 256, 256);
    wconv_k<<<dim3(256), blk, 0, stream>>>(Ws1, ws1, 256, 256);
    wconv_k<<<dim3(256), blk, 0, stream>>>(Wn1, wn1, 256, 256);
    wconv_k<<<dim3(64),  blk, 0, stream>>>(Ws2, ws2, 256, 64);
    wconv_k<<<dim3(64),  blk, 0, stream>>>(Wn2, wn2, 256, 64);

    // h0 = relu(x @ Wfc + bfc)   [f32 in, bf16 out]  512 rows/block
    gemm_lds<16, 4, true, false, true, true><<<dim3(N0c / 512), dim3(512), 0, stream>>>(
        x, nullptr, wfc, nullptr, bfc, h0);

    // ---- layer 0 ----
    build_and_aggregate(h0, src0, dst0, N1c, E0, hist, offs, bsum, ssrc, agg, stream);
    gemm_lds<16, 2, true, true, false, true><<<dim3(N1c / 256), dim3(512), 0, stream>>>(
        h0, agg, ws0, wn0, b0, h1);

    // ---- layer 1 ----
    build_and_aggregate(h1, src1, dst1, N2c, E1, hist, offs, bsum, ssrc, agg, stream);
    gemm_lds<16, 2, true, true, false, true><<<dim3(N2c / 256), dim3(512), 0, stream>>>(
        h1, agg, ws1, wn1, b1, h2);

    // ---- layer 2: out width 64, f32 out, no relu ----
    build_and_aggregate(h2, src2, dst2, N3c, E2, hist, offs, bsum, ssrc, agg, stream);
    gemm_lds<4, 1, false, true, false, false><<<dim3(N3c / 128), dim3(512), 0, stream>>>(
        h2, agg, ws2, wn2, b2, (float*)d_out);
}

// Round 7
// 1019.539 us; speedup vs baseline: 2.5775x; 2.5775x over previous
//
#include <hip/hip_runtime.h>

// GraphSAGE: x(524288,256) -> FC relu -> 3x sage_conv -> out(8192,64)
// R7: K-phased B-in-LDS MFMA GEMM via global_load_lds with pre-swizzled source,
//     SPW=1 (no spill), 64KB LDS (2 blocks/CU). bf16 activations, CSR pull-agg.
constexpr int N0c = 524288, N1c = 262144, N2c = 65536, N3c = 8192;

typedef __attribute__((ext_vector_type(8))) short   bf16x8;
typedef __attribute__((ext_vector_type(4))) float   f32x4;
typedef __attribute__((ext_vector_type(4))) unsigned short u16x4;

__device__ inline unsigned short f2bf(float f) {
    union { float f; unsigned u; } v; v.f = f;
    unsigned r = v.u + 0x7FFF + ((v.u >> 16) & 1);   // RNE
    return (unsigned short)(r >> 16);
}
__device__ inline float bf2f(unsigned short u) {
    union { unsigned u; float f; } v; v.u = ((unsigned)u) << 16;
    return v.f;
}

__device__ inline void glds16(const void* g, void* l) {
    __builtin_amdgcn_global_load_lds(
        (const __attribute__((address_space(1))) unsigned int*)g,
        (__attribute__((address_space(3))) unsigned int*)l, 16, 0, 0);
}

// transpose + cast one weight: Wt[n][k] = bf16(W[k][n]); K is always 256 here
__global__ __launch_bounds__(256)
void wconv_k(const float* __restrict__ W, unsigned short* __restrict__ Wt, int K, int N)
{
    const int i = blockIdx.x * 256 + threadIdx.x;   // over K*N
    if (i >= K * N) return;
    const int k = i / N, n = i % N;
    Wt[n * K + k] = f2bf(W[i]);
}

__device__ inline bf16x8 pack_bf8(const float* p) {
    const f32x4 u = *(const f32x4*)p;
    const f32x4 v = *(const f32x4*)(p + 4);
    bf16x8 t;
    #pragma unroll
    for (int j = 0; j < 4; ++j) {
        t[j]     = (short)f2bf(u[j]);
        t[j + 4] = (short)f2bf(v[j]);
    }
    return t;
}

// C[M x N] = act( A1 @ Wt1^T (+ A2 @ Wt2^T) + b ), K=256, N=NT*16.
// 512 thr = 8 waves, wave owns one 16-row strip (acc = NT*4 regs, persistent).
// Per phase: stage KC cols of W1 (and W2 if DUAL) into 64KB LDS via
// global_load_lds with pre-swizzled source; compute; barrier; restage.
template<int NT, int KC, bool DUAL, bool RELU, bool A_F32, bool OUT_BF16>
__global__ __launch_bounds__(512, 2)
void gemm2(const void* __restrict__ A1v, const void* __restrict__ A2v,
           const unsigned short* __restrict__ Wt1,
           const unsigned short* __restrict__ Wt2,
           const float* __restrict__ bias, void* __restrict__ Cv)
{
    constexpr int N     = NT * 16;
    constexpr int PH    = 256 / KC;                  // phases
    constexpr int SLOTS = KC / 8;                    // 16B granules per row-chunk
    constexpr int GPM   = N * SLOTS;                 // granules per matrix/phase
    constexpr int TOTG  = GPM * (DUAL ? 2 : 1);      // == 4096 (64 KB)
    static_assert(TOTG == 4096, "LDS sizing");
    __shared__ unsigned short Bs[TOTG * 8];

    const int t    = threadIdx.x;
    const int lane = t & 63;
    const int wv   = t >> 6;                 // 0..7
    const int col  = lane & 15;              // B col-in-tile / A row-in-strip
    const int kg   = lane >> 4;              // k-group
    const int swz  = (col & 7) << 3;         // read-side XOR (ushort units)
    const long row0 = (long)blockIdx.x * 128 + wv * 16;

    const unsigned short* A1h = (const unsigned short*)A1v;
    const float*          A1f = (const float*)A1v;
    const unsigned short* A2h = (const unsigned short*)A2v;

    f32x4 acc[NT];
    #pragma unroll
    for (int nt = 0; nt < NT; ++nt) acc[nt] = (f32x4){0.f, 0.f, 0.f, 0.f};

    const long ar = (row0 + col) * 256;

    for (int kh = 0; kh < PH; ++kh) {
        if (kh) __syncthreads();             // prior phase's LDS reads done
        // ---- stage: linear LDS dest, pre-swizzled global source ----
        #pragma unroll
        for (int it = 0; it < TOTG / 512; ++it) {    // 8 iters, 1KB/wave each
            const int g  = it * 512 + t;             // granule id
            const int m  = DUAL ? (g / GPM) : 0;
            const int gm = DUAL ? (g % GPM) : g;
            const int n  = gm / SLOTS;
            const int s  = gm % SLOTS;
            const int ss = s ^ (n & 7);              // involution swizzle
            const unsigned short* srcb =
                (m ? Wt2 : Wt1) + n * 256 + kh * KC + ss * 8;
            glds16(srcb, &Bs[(it * 512 + wv * 64) * 8]);
        }
        __syncthreads();                     // drains vmcnt(0)

        #pragma unroll
        for (int k0 = 0; k0 < KC; k0 += 32) {
            const int kx = (k0 + kg * 8) ^ swz;
            const long ac = ar + kh * KC + k0 + kg * 8;
            bf16x8 a1, a2;
            if constexpr (A_F32) a1 = pack_bf8(&A1f[ac]);
            else                 a1 = *(const bf16x8*)&A1h[ac];
            if constexpr (DUAL)  a2 = *(const bf16x8*)&A2h[ac];
            #pragma unroll
            for (int nt = 0; nt < NT; ++nt) {
                const bf16x8 b1 = *(const bf16x8*)&Bs[(nt * 16 + col) * KC + kx];
                acc[nt] = __builtin_amdgcn_mfma_f32_16x16x32_bf16(a1, b1, acc[nt], 0, 0, 0);
                if constexpr (DUAL) {
                    const bf16x8 b2 = *(const bf16x8*)&Bs[GPM * 8 + (nt * 16 + col) * KC + kx];
                    acc[nt] = __builtin_amdgcn_mfma_f32_16x16x32_bf16(a2, b2, acc[nt], 0, 0, 0);
                }
            }
        }
    }

    // ---- epilogue ----
    #pragma unroll
    for (int nt = 0; nt < NT; ++nt) {
        const int c = nt * 16 + col;
        const float bb = bias[c];
        #pragma unroll
        for (int rr = 0; rr < 4; ++rr) {
            const long row = row0 + kg * 4 + rr;
            float o = acc[nt][rr] + bb;
            if constexpr (RELU) o = fmaxf(o, 0.f);
            if constexpr (OUT_BF16)
                ((unsigned short*)Cv)[row * N + c] = f2bf(o);
            else
                ((float*)Cv)[row * N + c] = o;
        }
    }
}

// ---- CSR build: counting sort of edges by dst ----

__global__ __launch_bounds__(256)
void hist_k(const int* __restrict__ dst, int* __restrict__ hist, int E)
{
    const int i = blockIdx.x * 256 + threadIdx.x;
    if (i < E) atomicAdd(&hist[dst[i]], 1);
}

__global__ __launch_bounds__(256)
void scan1_k(const int* __restrict__ hist, int* __restrict__ offs,
             int* __restrict__ bsum, int n)
{
    __shared__ int sm[256];
    const int t = threadIdx.x;
    const int base = blockIdx.x * 1024 + t * 4;
    int4 v = make_int4(0, 0, 0, 0);
    if (base < n) v = *(const int4*)&hist[base];
    const int s = v.x + v.y + v.z + v.w;
    int val = s;
    sm[t] = val; __syncthreads();
    #pragma unroll
    for (int off = 1; off < 256; off <<= 1) {
        const int add = (t >= off) ? sm[t - off] : 0;
        __syncthreads();
        val += add;
        sm[t] = val;
        __syncthreads();
    }
    const int excl = val - s;
    if (base < n) {
        offs[base]     = excl;
        offs[base + 1] = excl + v.x;
        offs[base + 2] = excl + v.x + v.y;
        offs[base + 3] = excl + v.x + v.y + v.z;
    }
    if (t == 255) bsum[blockIdx.x] = val;
}

__global__ __launch_bounds__(256)
void scan2_k(int* __restrict__ bsum, int nb)
{
    __shared__ int sm[256];
    const int t = threadIdx.x;
    const int s = (t < nb) ? bsum[t] : 0;
    int val = s;
    sm[t] = val; __syncthreads();
    #pragma unroll
    for (int off = 1; off < 256; off <<= 1) {
        const int add = (t >= off) ? sm[t - off] : 0;
        __syncthreads();
        val += add;
        sm[t] = val;
        __syncthreads();
    }
    if (t < nb) bsum[t] = val - s;
}

__global__ __launch_bounds__(256)
void scan3_k(int* __restrict__ offs, const int* __restrict__ bsum)
{
    const int i = blockIdx.x * 256 + threadIdx.x;
    offs[i] += bsum[i >> 10];
}

__global__ __launch_bounds__(256)
void fill_k(const int* __restrict__ src, const int* __restrict__ dst,
            const int* __restrict__ offs, int* __restrict__ hist,
            int* __restrict__ ssrc, int E)
{
    const int i = blockIdx.x * 256 + threadIdx.x;
    if (i < E) {
        const int d = dst[i];
        const int p = atomicAdd(&hist[d], -1) - 1;
        ssrc[offs[d] + p] = src[i];
    }
}

// one wave per dst row: gather+mean bf16 h[src] rows (512 B each), no atomics
__global__ __launch_bounds__(256)
void agg_k(const unsigned short* __restrict__ h, const int* __restrict__ ssrc,
           const int* __restrict__ offs, unsigned short* __restrict__ agg,
           int n, int E)
{
    const int w    = blockIdx.x * 4 + (threadIdx.x >> 6);
    const int lane = threadIdx.x & 63;
    if (w >= n) return;
    const int beg = offs[w];
    const int end = (w == n - 1) ? E : offs[w + 1];
    float acc[4] = {0.f, 0.f, 0.f, 0.f};
    int j = beg;
    for (; j + 7 < end; j += 8) {                  // 8 gathers in flight
        int s[8];
        #pragma unroll
        for (int q = 0; q < 8; ++q) s[q] = ssrc[j + q];
        u16x4 v[8];
        #pragma unroll
        for (int q = 0; q < 8; ++q)
            v[q] = *(const u16x4*)&h[(size_t)s[q] * 256 + lane * 4];
        #pragma unroll
        for (int q = 0; q < 8; ++q)
            #pragma unroll
            for (int c = 0; c < 4; ++c) acc[c] += bf2f(v[q][c]);
    }
    for (; j < end; ++j) {
        const u16x4 v0 = *(const u16x4*)&h[(size_t)ssrc[j] * 256 + lane * 4];
        #pragma unroll
        for (int c = 0; c < 4; ++c) acc[c] += bf2f(v0[c]);
    }
    const float inv = 1.0f / fmaxf((float)(end - beg), 1.0f);
    u16x4 o;
    #pragma unroll
    for (int c = 0; c < 4; ++c) o[c] = f2bf(acc[c] * inv);
    *(u16x4*)&agg[(size_t)w * 256 + lane * 4] = o;
}

static void build_and_aggregate(const unsigned short* h, const int* src, const int* dst,
                                int n, int E, int* hist, int* offs, int* bsum,
                                int* ssrc, unsigned short* agg, hipStream_t stream)
{
    const dim3 blk(256);
    hipMemsetAsync(hist, 0, (size_t)n * 4, stream);
    hist_k<<<dim3((E + 255) / 256), blk, 0, stream>>>(dst, hist, E);
    scan1_k<<<dim3(n / 1024), blk, 0, stream>>>(hist, offs, bsum, n);
    scan2_k<<<dim3(1), blk, 0, stream>>>(bsum, n / 1024);
    scan3_k<<<dim3(n / 256), blk, 0, stream>>>(offs, bsum);
    fill_k<<<dim3((E + 255) / 256), blk, 0, stream>>>(src, dst, offs, hist, ssrc, E);
    agg_k<<<dim3(n / 4), blk, 0, stream>>>(h, ssrc, offs, agg, n, E);
}

extern "C" void kernel_launch(void* const* d_in, const int* in_sizes, int n_in,
                              void* d_out, int out_size, void* d_ws, size_t ws_size,
                              hipStream_t stream)
{
    const float* x    = (const float*)d_in[0];
    const int*   src0 = (const int*)d_in[1];
    const int*   dst0 = (const int*)d_in[2];
    const int*   src1 = (const int*)d_in[3];
    const int*   dst1 = (const int*)d_in[4];
    const int*   src2 = (const int*)d_in[5];
    const int*   dst2 = (const int*)d_in[6];
    const float* Wfc  = (const float*)d_in[10];
    const float* bfc  = (const float*)d_in[11];
    const float* Ws0  = (const float*)d_in[12];
    const float* Wn0  = (const float*)d_in[13];
    const float* b0   = (const float*)d_in[14];
    const float* Ws1  = (const float*)d_in[15];
    const float* Wn1  = (const float*)d_in[16];
    const float* b1   = (const float*)d_in[17];
    const float* Ws2  = (const float*)d_in[18];
    const float* Wn2  = (const float*)d_in[19];
    const float* b2   = (const float*)d_in[20];
    const int E0 = in_sizes[1], E1 = in_sizes[3], E2 = in_sizes[5];

    char* ws = (char*)d_ws;
    unsigned short* h0   = (unsigned short*)ws;                    // 256 MiB
    unsigned short* h1   = (unsigned short*)(ws + (256ULL << 20)); // 128 MiB
    unsigned short* h2   = (unsigned short*)(ws + (384ULL << 20)); //  32 MiB
    unsigned short* agg  = (unsigned short*)(ws + (416ULL << 20)); // 128 MiB
    unsigned short* Wt   = (unsigned short*)(ws + (544ULL << 20)); //   1 MiB
    int*            hist = (int*)(ws + (545ULL << 20));            //   1 MiB
    int*            offs = (int*)(ws + (546ULL << 20));            //   1 MiB
    int*            bsum = (int*)(ws + (547ULL << 20));            //   4 KiB
    int*            ssrc = (int*)(ws + (548ULL << 20));            // <=10.5 MiB

    unsigned short* wfc = Wt;
    unsigned short* ws0 = Wt + 65536;
    unsigned short* wn0 = Wt + 131072;
    unsigned short* ws1 = Wt + 196608;
    unsigned short* wn1 = Wt + 262144;
    unsigned short* ws2 = Wt + 327680;
    unsigned short* wn2 = Wt + 344064;

    const dim3 blk(256);

    // weights -> bf16 transposed [N][K]
    wconv_k<<<dim3(256), blk, 0, stream>>>(Wfc, wfc, 256, 256);
    wconv_k<<<dim3(256), blk, 0, stream>>>(Ws0, ws0, 256, 256);
    wconv_k<<<dim3(256), blk, 0, stream>>>(Wn0, wn0, 256, 256);
    wconv_k<<<dim3(256), blk, 0, stream>>>(Ws1, ws1, 256, 256);
    wconv_k<<<dim3(256), blk, 0, stream>>>(Wn1, wn1, 256, 256);
    wconv_k<<<dim3(64),  blk, 0, stream>>>(Ws2, ws2, 256, 64);
    wconv_k<<<dim3(64),  blk, 0, stream>>>(Wn2, wn2, 256, 64);

    // h0 = relu(x @ Wfc + bfc)   [f32 in, bf16 out]  128 rows/block
    gemm2<16, 128, false, true, true, true><<<dim3(N0c / 128), dim3(512), 0, stream>>>(
        x, nullptr, wfc, nullptr, bfc, h0);

    // ---- layer 0 ----
    build_and_aggregate(h0, src0, dst0, N1c, E0, hist, offs, bsum, ssrc, agg, stream);
    gemm2<16, 64, true, true, false, true><<<dim3(N1c / 128), dim3(512), 0, stream>>>(
        h0, agg, ws0, wn0, b0, h1);

    // ---- layer 1 ----
    build_and_aggregate(h1, src1, dst1, N2c, E1, hist, offs, bsum, ssrc, agg, stream);
    gemm2<16, 64, true, true, false, true><<<dim3(N2c / 128), dim3(512), 0, stream>>>(
        h1, agg, ws1, wn1, b1, h2);

    // ---- layer 2: out width 64, f32 out, no relu ----
    build_and_aggregate(h2, src2, dst2, N3c, E2, hist, offs, bsum, ssrc, agg, stream);
    gemm2<4, 256, true, false, false, false><<<dim3(N3c / 128), dim3(512), 0, stream>>>(
        h2, agg, ws2, wn2, b2, (float*)d_out);
}